// Round 1
// baseline (752.734 us; speedup 1.0000x reference)
//
#include <hip/hip_runtime.h>

#define DIM 64

__global__ void k_deg(const int* __restrict__ dst, float* __restrict__ deg, int E) {
    int e = blockIdx.x * blockDim.x + threadIdx.x;
    if (e < E) atomicAdd(&deg[dst[e]], 1.0f);
}

__global__ void k_dinv(float* __restrict__ deg, int n) {
    int i = blockIdx.x * blockDim.x + threadIdx.x;
    if (i < n) { float d = deg[i]; deg[i] = d > 0.0f ? rsqrtf(d) : 0.0f; }
}

__global__ void k_norm(const int* __restrict__ src, const int* __restrict__ dst,
                       const float* __restrict__ dinv, float* __restrict__ nrm, int E) {
    int e = blockIdx.x * blockDim.x + threadIdx.x;
    if (e < E) nrm[e] = dinv[src[e]] * dinv[dst[e]];
}

// out1 = E0, acc = E0, xa = 0, xb = 0   (n4 = N*DIM/4)
__global__ void k_init(const float4* __restrict__ e0, float4* __restrict__ out1,
                       float4* __restrict__ acc, float4* __restrict__ xa,
                       float4* __restrict__ xb, int n4) {
    int i = blockIdx.x * blockDim.x + threadIdx.x;
    if (i < n4) {
        float4 v = e0[i];
        out1[i] = v;
        acc[i]  = v;
        float4 z = make_float4(0.f, 0.f, 0.f, 0.f);
        xa[i] = z;
        xb[i] = z;
    }
}

// one wave (64 lanes) per edge; lane = feature index
__global__ void k_scatter(const float* __restrict__ x, const int* __restrict__ src,
                          const int* __restrict__ dst, const float* __restrict__ nrm,
                          float* __restrict__ xn, int E) {
    int e    = blockIdx.x * (blockDim.x >> 6) + (threadIdx.x >> 6);
    int lane = threadIdx.x & 63;
    if (e >= E) return;
    int   s = src[e];
    int   d = dst[e];
    float w = nrm[e];
    atomicAdd(&xn[d * DIM + lane], w * x[s * DIM + lane]);
}

// acc += xn ; if (xz) xz = 0
__global__ void k_accum(float4* __restrict__ acc, const float4* __restrict__ xn,
                        float4* __restrict__ xz, int n4) {
    int i = blockIdx.x * blockDim.x + threadIdx.x;
    if (i < n4) {
        float4 a = acc[i], b = xn[i];
        a.x += b.x; a.y += b.y; a.z += b.z; a.w += b.w;
        acc[i] = a;
        if (xz) xz[i] = make_float4(0.f, 0.f, 0.f, 0.f);
    }
}

// out2 = (acc + xn) * 0.25
__global__ void k_final(const float4* __restrict__ acc, const float4* __restrict__ xn,
                        float4* __restrict__ out2, int n4) {
    int i = blockIdx.x * blockDim.x + threadIdx.x;
    if (i < n4) {
        float4 a = acc[i], b = xn[i];
        float4 r;
        r.x = (a.x + b.x) * 0.25f;
        r.y = (a.y + b.y) * 0.25f;
        r.z = (a.z + b.z) * 0.25f;
        r.w = (a.w + b.w) * 0.25f;
        out2[i] = r;
    }
}

extern "C" void kernel_launch(void* const* d_in, const int* in_sizes, int n_in,
                              void* d_out, int out_size, void* d_ws, size_t ws_size,
                              hipStream_t stream) {
    const float* E0  = (const float*)d_in[0];
    const int*   idx = (const int*)d_in[1];

    const int N = in_sizes[0] / DIM;      // 100000
    const int E = in_sizes[1] / 2;        // 1000000

    const int* src = idx;
    const int* dst = idx + E;

    float* out1 = (float*)d_out;                  // E0 copy
    float* out2 = (float*)d_out + (size_t)N * DIM; // final embeddings

    // workspace layout (all float, all 16B-aligned: N and E divisible by 4)
    float* ws  = (float*)d_ws;
    float* nrm = ws;                       // E
    float* deg = nrm + E;                  // N  (deg -> dinv in place)
    float* xa  = deg + N;                  // N*DIM
    float* xb  = xa + (size_t)N * DIM;     // N*DIM
    float* acc = xb + (size_t)N * DIM;     // N*DIM

    const int n4 = N * DIM / 4;

    hipMemsetAsync(deg, 0, (size_t)N * sizeof(float), stream);

    k_deg <<<(E + 255) / 256, 256, 0, stream>>>(dst, deg, E);
    k_dinv<<<(N + 255) / 256, 256, 0, stream>>>(deg, N);
    k_norm<<<(E + 255) / 256, 256, 0, stream>>>(src, dst, deg, nrm, E);

    k_init<<<(n4 + 255) / 256, 256, 0, stream>>>((const float4*)E0, (float4*)out1,
                                                 (float4*)acc, (float4*)xa,
                                                 (float4*)xb, n4);

    // layer 1: E0 -> xa
    k_scatter<<<(E + 3) / 4, 256, 0, stream>>>(E0, src, dst, nrm, xa, E);
    k_accum  <<<(n4 + 255) / 256, 256, 0, stream>>>((float4*)acc, (const float4*)xa,
                                                    (float4*)nullptr, n4);
    // layer 2: xa -> xb
    k_scatter<<<(E + 3) / 4, 256, 0, stream>>>(xa, src, dst, nrm, xb, E);
    k_accum  <<<(n4 + 255) / 256, 256, 0, stream>>>((float4*)acc, (const float4*)xb,
                                                    (float4*)xa, n4); // also zeroes xa
    // layer 3: xb -> xa
    k_scatter<<<(E + 3) / 4, 256, 0, stream>>>(xb, src, dst, nrm, xa, E);
    k_final  <<<(n4 + 255) / 256, 256, 0, stream>>>((const float4*)acc, (const float4*)xa,
                                                    (float4*)out2, n4);
}

// Round 3
// 316.529 us; speedup vs baseline: 2.3781x; 2.3781x over previous
//
#include <hip/hip_runtime.h>

#define DIM 64
#define SBLK 256

// ---- degree histogram (int atomics) ----
__global__ void k_hist(const int* __restrict__ dst, int* __restrict__ deg, int E) {
    int e = blockIdx.x * blockDim.x + threadIdx.x;
    if (e < E) atomicAdd(&deg[dst[e]], 1);
}

__global__ void k_dinv(const int* __restrict__ deg, float* __restrict__ dinv, int n) {
    int i = blockIdx.x * blockDim.x + threadIdx.x;
    if (i < n) { int c = deg[i]; dinv[i] = c > 0 ? rsqrtf((float)c) : 0.0f; }
}

// ---- block sums for scan ----
__global__ void k_bsum(const int* __restrict__ deg, int* __restrict__ bsum, int N) {
    __shared__ int sm[SBLK];
    int i = blockIdx.x * SBLK + threadIdx.x;
    sm[threadIdx.x] = (i < N) ? deg[i] : 0;
    __syncthreads();
    for (int s = SBLK / 2; s > 0; s >>= 1) {
        if (threadIdx.x < s) sm[threadIdx.x] += sm[threadIdx.x + s];
        __syncthreads();
    }
    if (threadIdx.x == 0) bsum[blockIdx.x] = sm[0];
}

// ---- single-block exclusive scan of block sums (nb <= 1024) ----
__global__ void k_scanb(int* __restrict__ bsum, int nb, int* __restrict__ offN, int E) {
    __shared__ int sm[1024];
    int t = threadIdx.x;
    int v = (t < nb) ? bsum[t] : 0;
    sm[t] = v;
    __syncthreads();
    for (int s = 1; s < 1024; s <<= 1) {
        int u = (t >= s) ? sm[t - s] : 0;
        __syncthreads();
        sm[t] += u;
        __syncthreads();
    }
    if (t < nb) bsum[t] = sm[t] - v;   // exclusive
    if (t == 0) *offN = E;             // off[N] = E
}

// ---- per-block exclusive scan + block offset -> off, cursor ----
__global__ void k_scanfin(const int* __restrict__ deg, const int* __restrict__ bsum,
                          int* __restrict__ off, int* __restrict__ cursor, int N) {
    __shared__ int sm[SBLK];
    int i = blockIdx.x * SBLK + threadIdx.x;
    int v = (i < N) ? deg[i] : 0;
    sm[threadIdx.x] = v;
    __syncthreads();
    for (int s = 1; s < SBLK; s <<= 1) {
        int u = (threadIdx.x >= s) ? sm[threadIdx.x - s] : 0;
        __syncthreads();
        sm[threadIdx.x] += u;
        __syncthreads();
    }
    int ex = sm[threadIdx.x] - v + bsum[blockIdx.x];
    if (i < N) { off[i] = ex; cursor[i] = ex; }
}

// ---- CSR fill: ticket allocation per dst ----
__global__ void k_fill(const int* __restrict__ src, const int* __restrict__ dst,
                       const float* __restrict__ dinv, int* __restrict__ cursor,
                       int* __restrict__ col, float* __restrict__ w, int E) {
    int e = blockIdx.x * blockDim.x + threadIdx.x;
    if (e >= E) return;
    int s = src[e], d = dst[e];
    int p = atomicAdd(&cursor[d], 1);
    col[p] = s;
    w[p] = dinv[s];            // dinv[dst] factored out, applied per node
}

// ---- out1 = E0, acc(out2) = E0 ----
__global__ void k_init(const float4* __restrict__ e0, float4* __restrict__ out1,
                       float4* __restrict__ acc, int n4) {
    int i = blockIdx.x * blockDim.x + threadIdx.x;
    if (i < n4) { float4 v = e0[i]; out1[i] = v; acc[i] = v; }
}

// ---- pull-propagate: 1 wave per node, 4 edge slots x 16 float4 lanes ----
// mode 0: xn = dinv*sum ; acc += xn
// mode 1: acc = (acc + dinv*sum) * 0.25   (final layer; xn unused)
__global__ __launch_bounds__(256) void k_prop(const float4* __restrict__ x,
        const int* __restrict__ off, const int* __restrict__ col,
        const float* __restrict__ w, const float* __restrict__ dinv,
        float4* __restrict__ xn, float4* __restrict__ acc, int N, int mode) {
    int wid = (blockIdx.x * 256 + threadIdx.x) >> 6;   // global wave id = node id
    if (wid >= N) return;
    int lane = threadIdx.x & 63;
    int es   = lane >> 4;      // edge slot 0..3
    int ch   = lane & 15;      // float4 chunk 0..15
    int s = off[wid], e = off[wid + 1];

    float4 a = make_float4(0.f, 0.f, 0.f, 0.f);
    for (int j = s + es; j < e; j += 4) {
        int   c  = col[j];
        float wt = w[j];
        float4 v = x[(size_t)c * 16 + ch];
        a.x += wt * v.x; a.y += wt * v.y; a.z += wt * v.z; a.w += wt * v.w;
    }
    // reduce across the 4 edge slots (lanes differing in bits 4,5)
    a.x += __shfl_xor(a.x, 16); a.y += __shfl_xor(a.y, 16);
    a.z += __shfl_xor(a.z, 16); a.w += __shfl_xor(a.w, 16);
    a.x += __shfl_xor(a.x, 32); a.y += __shfl_xor(a.y, 32);
    a.z += __shfl_xor(a.z, 32); a.w += __shfl_xor(a.w, 32);

    if (es == 0) {
        float dv = dinv[wid];
        size_t o = (size_t)wid * 16 + ch;
        float4 r = make_float4(a.x * dv, a.y * dv, a.z * dv, a.w * dv);
        float4 t = acc[o];
        if (mode == 0) {
            xn[o] = r;
            t.x += r.x; t.y += r.y; t.z += r.z; t.w += r.w;
            acc[o] = t;
        } else {
            t.x = (t.x + r.x) * 0.25f; t.y = (t.y + r.y) * 0.25f;
            t.z = (t.z + r.z) * 0.25f; t.w = (t.w + r.w) * 0.25f;
            acc[o] = t;
        }
    }
}

extern "C" void kernel_launch(void* const* d_in, const int* in_sizes, int n_in,
                              void* d_out, int out_size, void* d_ws, size_t ws_size,
                              hipStream_t stream) {
    const float* E0  = (const float*)d_in[0];
    const int*   idx = (const int*)d_in[1];

    const int N = in_sizes[0] / DIM;   // 100000
    const int E = in_sizes[1] / 2;     // 1000000

    const int* src = idx;
    const int* dst = idx + E;

    float* out1 = (float*)d_out;                     // E0 copy
    float* out2 = (float*)d_out + (size_t)N * DIM;   // acc / final embeddings

    const int NB = (N + SBLK - 1) / SBLK;            // scan blocks (391)

    // workspace layout — every carve rounded to 16 B so float4 casts are aligned
    char* ws = (char*)d_ws;
    auto carve = [&](size_t bytes) -> char* {
        char* p = ws;
        ws += (bytes + 15) & ~(size_t)15;
        return p;
    };
    int*   deg    = (int*)  carve((size_t)N * 4);
    int*   off    = (int*)  carve((size_t)(N + 1) * 4);
    int*   cursor = (int*)  carve((size_t)N * 4);
    int*   bsum   = (int*)  carve((size_t)NB * 4);
    float* dinv   = (float*)carve((size_t)N * 4);
    int*   col    = (int*)  carve((size_t)E * 4);
    float* w      = (float*)carve((size_t)E * 4);
    float* xa     = (float*)carve((size_t)N * DIM * 4);
    float* xb     = (float*)carve((size_t)N * DIM * 4);

    const int n4 = N * DIM / 4;

    hipMemsetAsync(deg, 0, (size_t)N * sizeof(int), stream);

    k_hist   <<<(E + 255) / 256, 256, 0, stream>>>(dst, deg, E);
    k_dinv   <<<(N + 255) / 256, 256, 0, stream>>>(deg, dinv, N);
    k_bsum   <<<NB, SBLK, 0, stream>>>(deg, bsum, N);
    k_scanb  <<<1, 1024, 0, stream>>>(bsum, NB, &off[N], E);
    k_scanfin<<<NB, SBLK, 0, stream>>>(deg, bsum, off, cursor, N);
    k_fill   <<<(E + 255) / 256, 256, 0, stream>>>(src, dst, dinv, cursor, col, w, E);

    k_init   <<<(n4 + 255) / 256, 256, 0, stream>>>((const float4*)E0, (float4*)out1,
                                                    (float4*)out2, n4);

    const int PB = (N + 3) / 4;   // one 64-lane wave per node, 4 waves per 256-thread block
    // layer 1: E0 -> xa
    k_prop<<<PB, 256, 0, stream>>>((const float4*)E0, off, col, w, dinv,
                                   (float4*)xa, (float4*)out2, N, 0);
    // layer 2: xa -> xb
    k_prop<<<PB, 256, 0, stream>>>((const float4*)xa, off, col, w, dinv,
                                   (float4*)xb, (float4*)out2, N, 0);
    // layer 3: xb -> (final, fused into out2)
    k_prop<<<PB, 256, 0, stream>>>((const float4*)xb, off, col, w, dinv,
                                   (float4*)nullptr, (float4*)out2, N, 1);
}

// Round 4
// 309.329 us; speedup vs baseline: 2.4334x; 1.0233x over previous
//
#include <hip/hip_runtime.h>

#define DIM 64
#define SBLK 256

// ---- degree histogram (int atomics) ----
__global__ void k_hist(const int* __restrict__ dst, int* __restrict__ deg, int E) {
    int e = blockIdx.x * blockDim.x + threadIdx.x;
    if (e < E) atomicAdd(&deg[dst[e]], 1);
}

// ---- block sums for scan ----
__global__ void k_bsum(const int* __restrict__ deg, int* __restrict__ bsum, int N) {
    __shared__ int sm[SBLK];
    int i = blockIdx.x * SBLK + threadIdx.x;
    sm[threadIdx.x] = (i < N) ? deg[i] : 0;
    __syncthreads();
    for (int s = SBLK / 2; s > 0; s >>= 1) {
        if (threadIdx.x < s) sm[threadIdx.x] += sm[threadIdx.x + s];
        __syncthreads();
    }
    if (threadIdx.x == 0) bsum[blockIdx.x] = sm[0];
}

// ---- single-block exclusive scan of block sums (nb <= 1024) ----
__global__ void k_scanb(int* __restrict__ bsum, int nb, int* __restrict__ offN, int E) {
    __shared__ int sm[1024];
    int t = threadIdx.x;
    int v = (t < nb) ? bsum[t] : 0;
    sm[t] = v;
    __syncthreads();
    for (int s = 1; s < 1024; s <<= 1) {
        int u = (t >= s) ? sm[t - s] : 0;
        __syncthreads();
        sm[t] += u;
        __syncthreads();
    }
    if (t < nb) bsum[t] = sm[t] - v;   // exclusive
    if (t == 0) *offN = E;             // off[N] = E
}

// ---- per-block exclusive scan + block offset -> off, cursor; fused dinv ----
__global__ void k_scanfin(const int* __restrict__ deg, const int* __restrict__ bsum,
                          int* __restrict__ off, int* __restrict__ cursor,
                          float* __restrict__ dinv, int N) {
    __shared__ int sm[SBLK];
    int i = blockIdx.x * SBLK + threadIdx.x;
    int v = (i < N) ? deg[i] : 0;
    sm[threadIdx.x] = v;
    __syncthreads();
    for (int s = 1; s < SBLK; s <<= 1) {
        int u = (threadIdx.x >= s) ? sm[threadIdx.x - s] : 0;
        __syncthreads();
        sm[threadIdx.x] += u;
        __syncthreads();
    }
    int ex = sm[threadIdx.x] - v + bsum[blockIdx.x];
    if (i < N) {
        off[i] = ex;
        cursor[i] = ex;
        dinv[i] = v > 0 ? rsqrtf((float)v) : 0.0f;
    }
}

// ---- CSR fill: ticket allocation per dst; packed (col, w) single 8B store ----
__global__ void k_fill(const int* __restrict__ src, const int* __restrict__ dst,
                       const float* __restrict__ dinv, int* __restrict__ cursor,
                       int2* __restrict__ col2, int E) {
    int e = blockIdx.x * blockDim.x + threadIdx.x;
    if (e >= E) return;
    int s = src[e], d = dst[e];
    int p = atomicAdd(&cursor[d], 1);
    col2[p] = make_int2(s, __float_as_int(dinv[s]));  // dinv[dst] factored out
}

// ---- out1 = E0, acc(out2) = E0 ----
__global__ void k_init(const float4* __restrict__ e0, float4* __restrict__ out1,
                       float4* __restrict__ acc, int n4) {
    int i = blockIdx.x * blockDim.x + threadIdx.x;
    if (i < n4) { float4 v = e0[i]; out1[i] = v; acc[i] = v; }
}

// ---- pull-propagate: 1 wave per node, 4 edge slots x 16 float4 lanes ----
// mode 0: xn = dinv*sum ; acc += xn
// mode 1: acc = (acc + dinv*sum) * 0.25   (final layer; xn unused)
__global__ __launch_bounds__(256) void k_prop(const float4* __restrict__ x,
        const int* __restrict__ off, const int2* __restrict__ col2,
        const float* __restrict__ dinv,
        float4* __restrict__ xn, float4* __restrict__ acc, int N, int mode) {
    int wid = (blockIdx.x * 256 + threadIdx.x) >> 6;   // global wave id = node id
    if (wid >= N) return;
    int lane = threadIdx.x & 63;
    int es   = lane >> 4;      // edge slot 0..3
    int ch   = lane & 15;      // float4 chunk 0..15
    int s = off[wid], e = off[wid + 1];

    float4 a = make_float4(0.f, 0.f, 0.f, 0.f);
    for (int j = s + es; j < e; j += 4) {
        int2  cw = col2[j];
        float wt = __int_as_float(cw.y);
        float4 v = x[(size_t)cw.x * 16 + ch];
        a.x += wt * v.x; a.y += wt * v.y; a.z += wt * v.z; a.w += wt * v.w;
    }
    // reduce across the 4 edge slots (lanes differing in bits 4,5)
    a.x += __shfl_xor(a.x, 16); a.y += __shfl_xor(a.y, 16);
    a.z += __shfl_xor(a.z, 16); a.w += __shfl_xor(a.w, 16);
    a.x += __shfl_xor(a.x, 32); a.y += __shfl_xor(a.y, 32);
    a.z += __shfl_xor(a.z, 32); a.w += __shfl_xor(a.w, 32);

    if (es == 0) {
        float dv = dinv[wid];
        size_t o = (size_t)wid * 16 + ch;
        float4 r = make_float4(a.x * dv, a.y * dv, a.z * dv, a.w * dv);
        float4 t = acc[o];
        if (mode == 0) {
            xn[o] = r;
            t.x += r.x; t.y += r.y; t.z += r.z; t.w += r.w;
            acc[o] = t;
        } else {
            t.x = (t.x + r.x) * 0.25f; t.y = (t.y + r.y) * 0.25f;
            t.z = (t.z + r.z) * 0.25f; t.w = (t.w + r.w) * 0.25f;
            acc[o] = t;
        }
    }
}

extern "C" void kernel_launch(void* const* d_in, const int* in_sizes, int n_in,
                              void* d_out, int out_size, void* d_ws, size_t ws_size,
                              hipStream_t stream) {
    const float* E0  = (const float*)d_in[0];
    const int*   idx = (const int*)d_in[1];

    const int N = in_sizes[0] / DIM;   // 100000
    const int E = in_sizes[1] / 2;     // 1000000

    const int* src = idx;
    const int* dst = idx + E;

    float* out1 = (float*)d_out;                     // E0 copy
    float* out2 = (float*)d_out + (size_t)N * DIM;   // acc / final embeddings

    const int NB = (N + SBLK - 1) / SBLK;            // scan blocks (391)

    // workspace layout — every carve rounded to 16 B so float4/int2 casts are aligned
    char* ws = (char*)d_ws;
    auto carve = [&](size_t bytes) -> char* {
        char* p = ws;
        ws += (bytes + 15) & ~(size_t)15;
        return p;
    };
    int*   deg    = (int*)  carve((size_t)N * 4);
    int*   off    = (int*)  carve((size_t)(N + 1) * 4);
    int*   cursor = (int*)  carve((size_t)N * 4);
    int*   bsum   = (int*)  carve((size_t)NB * 4);
    float* dinv   = (float*)carve((size_t)N * 4);
    int2*  col2   = (int2*) carve((size_t)E * 8);
    float* xa     = (float*)carve((size_t)N * DIM * 4);
    float* xb     = (float*)carve((size_t)N * DIM * 4);

    const int n4 = N * DIM / 4;

    hipMemsetAsync(deg, 0, (size_t)N * sizeof(int), stream);

    k_hist   <<<(E + 255) / 256, 256, 0, stream>>>(dst, deg, E);
    k_bsum   <<<NB, SBLK, 0, stream>>>(deg, bsum, N);
    k_scanb  <<<1, 1024, 0, stream>>>(bsum, NB, &off[N], E);
    k_scanfin<<<NB, SBLK, 0, stream>>>(deg, bsum, off, cursor, dinv, N);
    k_fill   <<<(E + 255) / 256, 256, 0, stream>>>(src, dst, dinv, cursor, col2, E);

    k_init   <<<(n4 + 255) / 256, 256, 0, stream>>>((const float4*)E0, (float4*)out1,
                                                    (float4*)out2, n4);

    const int PB = (N + 3) / 4;   // one 64-lane wave per node, 4 waves per 256-thread block
    // layer 1: E0 -> xa
    k_prop<<<PB, 256, 0, stream>>>((const float4*)E0, off, col2, dinv,
                                   (float4*)xa, (float4*)out2, N, 0);
    // layer 2: xa -> xb
    k_prop<<<PB, 256, 0, stream>>>((const float4*)xa, off, col2, dinv,
                                   (float4*)xb, (float4*)out2, N, 0);
    // layer 3: xb -> (final, fused into out2)
    k_prop<<<PB, 256, 0, stream>>>((const float4*)xb, off, col2, dinv,
                                   (float4*)nullptr, (float4*)out2, N, 1);
}

// Round 5
// 260.785 us; speedup vs baseline: 2.8864x; 1.1861x over previous
//
#include <hip/hip_runtime.h>

#define DIM 64
#define SBLK 256

// ---- degree histogram + per-edge rank (ticket) ----
__global__ void k_hist(const int* __restrict__ dst, int* __restrict__ deg,
                       int* __restrict__ rank, int E) {
    int e = blockIdx.x * blockDim.x + threadIdx.x;
    if (e < E) rank[e] = atomicAdd(&deg[dst[e]], 1);
}

// ---- block sums for scan ----
__global__ void k_bsum(const int* __restrict__ deg, int* __restrict__ bsum, int N) {
    __shared__ int sm[SBLK];
    int i = blockIdx.x * SBLK + threadIdx.x;
    sm[threadIdx.x] = (i < N) ? deg[i] : 0;
    __syncthreads();
    for (int s = SBLK / 2; s > 0; s >>= 1) {
        if (threadIdx.x < s) sm[threadIdx.x] += sm[threadIdx.x + s];
        __syncthreads();
    }
    if (threadIdx.x == 0) bsum[blockIdx.x] = sm[0];
}

// ---- single-block exclusive scan of block sums (nb <= 1024) ----
__global__ void k_scanb(int* __restrict__ bsum, int nb, int* __restrict__ offN, int E) {
    __shared__ int sm[1024];
    int t = threadIdx.x;
    int v = (t < nb) ? bsum[t] : 0;
    sm[t] = v;
    __syncthreads();
    for (int s = 1; s < 1024; s <<= 1) {
        int u = (t >= s) ? sm[t - s] : 0;
        __syncthreads();
        sm[t] += u;
        __syncthreads();
    }
    if (t < nb) bsum[t] = sm[t] - v;   // exclusive
    if (t == 0) *offN = E;             // off[N] = E
}

// ---- per-block exclusive scan + block offset -> off; fused dinv & sqrt(deg) ----
__global__ void k_scanfin(const int* __restrict__ deg, const int* __restrict__ bsum,
                          int* __restrict__ off, float* __restrict__ dinv,
                          float* __restrict__ dsq, int N) {
    __shared__ int sm[SBLK];
    int i = blockIdx.x * SBLK + threadIdx.x;
    int v = (i < N) ? deg[i] : 0;
    sm[threadIdx.x] = v;
    __syncthreads();
    for (int s = 1; s < SBLK; s <<= 1) {
        int u = (threadIdx.x >= s) ? sm[threadIdx.x - s] : 0;
        __syncthreads();
        sm[threadIdx.x] += u;
        __syncthreads();
    }
    int ex = sm[threadIdx.x] - v + bsum[blockIdx.x];
    if (i < N) {
        off[i]  = ex;
        dinv[i] = v > 0 ? rsqrtf((float)v) : 0.0f;
        dsq[i]  = v > 0 ? sqrtf((float)v) : 0.0f;
    }
}

// ---- CSR fill: no atomics — slot = off[dst] + rank ----
__global__ void k_fill(const int* __restrict__ src, const int* __restrict__ dst,
                       const int* __restrict__ rank, const int* __restrict__ off,
                       int* __restrict__ col, int E) {
    int e = blockIdx.x * blockDim.x + threadIdx.x;
    if (e >= E) return;
    col[off[dst[e]] + rank[e]] = src[e];
}

// ---- out1 = E0 ; y0 = dinv * E0 ----
__global__ void k_init(const float4* __restrict__ e0, const float* __restrict__ dinv,
                       float4* __restrict__ out1, float4* __restrict__ y0, int n4) {
    int i = blockIdx.x * blockDim.x + threadIdx.x;
    if (i < n4) {
        float4 v = e0[i];
        out1[i] = v;
        float dv = dinv[i >> 4];
        y0[i] = make_float4(v.x * dv, v.y * dv, v.z * dv, v.w * dv);
    }
}

// ---- pull-propagate: y_out[d] = dinv[d]^2 * sum_{s->d} y_in[s] ----
// 1 wave per node, 4 edge slots x 16 float4 lanes
__global__ __launch_bounds__(256) void k_prop(const float4* __restrict__ y,
        const int* __restrict__ off, const int* __restrict__ col,
        const float* __restrict__ dinv, float4* __restrict__ yout, int N) {
    int wid = (blockIdx.x * 256 + threadIdx.x) >> 6;
    if (wid >= N) return;
    int lane = threadIdx.x & 63;
    int es   = lane >> 4;
    int ch   = lane & 15;
    int s = off[wid], e = off[wid + 1];

    float4 a = make_float4(0.f, 0.f, 0.f, 0.f);
    for (int j = s + es; j < e; j += 4) {
        float4 v = y[(size_t)col[j] * 16 + ch];
        a.x += v.x; a.y += v.y; a.z += v.z; a.w += v.w;
    }
    a.x += __shfl_xor(a.x, 16); a.y += __shfl_xor(a.y, 16);
    a.z += __shfl_xor(a.z, 16); a.w += __shfl_xor(a.w, 16);
    a.x += __shfl_xor(a.x, 32); a.y += __shfl_xor(a.y, 32);
    a.z += __shfl_xor(a.z, 32); a.w += __shfl_xor(a.w, 32);

    if (es == 0) {
        float dv = dinv[wid];
        float s2 = dv * dv;
        size_t o = (size_t)wid * 16 + ch;
        yout[o] = make_float4(s2 * a.x, s2 * a.y, s2 * a.z, s2 * a.w);
    }
}

// ---- final: out2 = 0.25*(E0 + sqrt(deg)*(y1+y2) + dinv*sum(y2[s])) ----
__global__ __launch_bounds__(256) void k_prop_final(const float4* __restrict__ y2,
        const int* __restrict__ off, const int* __restrict__ col,
        const float* __restrict__ dinv, const float* __restrict__ dsq,
        const float4* __restrict__ e0, const float4* __restrict__ y1b,
        const float4* __restrict__ y2b, float4* __restrict__ out2, int N) {
    int wid = (blockIdx.x * 256 + threadIdx.x) >> 6;
    if (wid >= N) return;
    int lane = threadIdx.x & 63;
    int es   = lane >> 4;
    int ch   = lane & 15;
    int s = off[wid], e = off[wid + 1];

    float4 a = make_float4(0.f, 0.f, 0.f, 0.f);
    for (int j = s + es; j < e; j += 4) {
        float4 v = y2[(size_t)col[j] * 16 + ch];
        a.x += v.x; a.y += v.y; a.z += v.z; a.w += v.w;
    }
    a.x += __shfl_xor(a.x, 16); a.y += __shfl_xor(a.y, 16);
    a.z += __shfl_xor(a.z, 16); a.w += __shfl_xor(a.w, 16);
    a.x += __shfl_xor(a.x, 32); a.y += __shfl_xor(a.y, 32);
    a.z += __shfl_xor(a.z, 32); a.w += __shfl_xor(a.w, 32);

    if (es == 0) {
        float dv = dinv[wid];      // x3 = dinv * sum
        float dq = dsq[wid];       // x1 + x2 = sqrt(deg) * (y1 + y2)
        size_t o = (size_t)wid * 16 + ch;
        float4 t  = e0[o];
        float4 a1 = y1b[o];
        float4 a2 = y2b[o];
        float4 r;
        r.x = 0.25f * (t.x + dq * (a1.x + a2.x) + dv * a.x);
        r.y = 0.25f * (t.y + dq * (a1.y + a2.y) + dv * a.y);
        r.z = 0.25f * (t.z + dq * (a1.z + a2.z) + dv * a.z);
        r.w = 0.25f * (t.w + dq * (a1.w + a2.w) + dv * a.w);
        out2[o] = r;
    }
}

extern "C" void kernel_launch(void* const* d_in, const int* in_sizes, int n_in,
                              void* d_out, int out_size, void* d_ws, size_t ws_size,
                              hipStream_t stream) {
    const float* E0  = (const float*)d_in[0];
    const int*   idx = (const int*)d_in[1];

    const int N = in_sizes[0] / DIM;   // 100000
    const int E = in_sizes[1] / 2;     // 1000000

    const int* src = idx;
    const int* dst = idx + E;

    float* out1 = (float*)d_out;                     // E0 copy
    float* out2 = (float*)d_out + (size_t)N * DIM;   // final embeddings

    const int NB = (N + SBLK - 1) / SBLK;            // scan blocks (391)

    // workspace layout — every carve rounded to 16 B so float4 casts are aligned
    char* ws = (char*)d_ws;
    auto carve = [&](size_t bytes) -> char* {
        char* p = ws;
        ws += (bytes + 15) & ~(size_t)15;
        return p;
    };
    int*   deg  = (int*)  carve((size_t)N * 4);
    int*   off  = (int*)  carve((size_t)(N + 1) * 4);
    int*   bsum = (int*)  carve((size_t)NB * 4);
    float* dinv = (float*)carve((size_t)N * 4);
    float* dsq  = (float*)carve((size_t)N * 4);
    int*   rank = (int*)  carve((size_t)E * 4);
    int*   col  = (int*)  carve((size_t)E * 4);
    float* y0   = (float*)carve((size_t)N * DIM * 4);
    float* y1   = (float*)carve((size_t)N * DIM * 4);
    float* y2   = (float*)carve((size_t)N * DIM * 4);

    const int n4 = N * DIM / 4;

    hipMemsetAsync(deg, 0, (size_t)N * sizeof(int), stream);

    k_hist   <<<(E + 255) / 256, 256, 0, stream>>>(dst, deg, rank, E);
    k_bsum   <<<NB, SBLK, 0, stream>>>(deg, bsum, N);
    k_scanb  <<<1, 1024, 0, stream>>>(bsum, NB, &off[N], E);
    k_scanfin<<<NB, SBLK, 0, stream>>>(deg, bsum, off, dinv, dsq, N);
    k_fill   <<<(E + 255) / 256, 256, 0, stream>>>(src, dst, rank, off, col, E);

    k_init   <<<(n4 + 255) / 256, 256, 0, stream>>>((const float4*)E0, dinv,
                                                    (float4*)out1, (float4*)y0, n4);

    const int PB = (N + 3) / 4;   // one 64-lane wave per node
    // layer 1: y0 -> y1
    k_prop<<<PB, 256, 0, stream>>>((const float4*)y0, off, col, dinv, (float4*)y1, N);
    // layer 2: y1 -> y2
    k_prop<<<PB, 256, 0, stream>>>((const float4*)y1, off, col, dinv, (float4*)y2, N);
    // layer 3 + final combine, fused
    k_prop_final<<<PB, 256, 0, stream>>>((const float4*)y2, off, col, dinv, dsq,
                                         (const float4*)E0, (const float4*)y1,
                                         (const float4*)y2, (float4*)out2, N);
}

// Round 6
// 210.673 us; speedup vs baseline: 3.5730x; 1.2379x over previous
//
#include <hip/hip_runtime.h>
#include <hip/hip_fp16.h>

#define DIM 64
#define SBLK 256

union H8 { uint4 u; __half2 h2[4]; };

// ---- degree histogram + per-edge rank (ticket) ----
__global__ void k_hist(const int* __restrict__ dst, int* __restrict__ deg,
                       int* __restrict__ rank, int E) {
    int e = blockIdx.x * blockDim.x + threadIdx.x;
    if (e < E) rank[e] = atomicAdd(&deg[dst[e]], 1);
}

// ---- block sums for scan ----
__global__ void k_bsum(const int* __restrict__ deg, int* __restrict__ bsum, int N) {
    __shared__ int sm[SBLK];
    int i = blockIdx.x * SBLK + threadIdx.x;
    sm[threadIdx.x] = (i < N) ? deg[i] : 0;
    __syncthreads();
    for (int s = SBLK / 2; s > 0; s >>= 1) {
        if (threadIdx.x < s) sm[threadIdx.x] += sm[threadIdx.x + s];
        __syncthreads();
    }
    if (threadIdx.x == 0) bsum[blockIdx.x] = sm[0];
}

// ---- single-block exclusive scan of block sums (nb <= 1024) ----
__global__ void k_scanb(int* __restrict__ bsum, int nb, int* __restrict__ offN, int E) {
    __shared__ int sm[1024];
    int t = threadIdx.x;
    int v = (t < nb) ? bsum[t] : 0;
    sm[t] = v;
    __syncthreads();
    for (int s = 1; s < 1024; s <<= 1) {
        int u = (t >= s) ? sm[t - s] : 0;
        __syncthreads();
        sm[t] += u;
        __syncthreads();
    }
    if (t < nb) bsum[t] = sm[t] - v;   // exclusive
    if (t == 0) *offN = E;             // off[N] = E
}

// ---- per-block exclusive scan + block offset -> off; fused dinv & sqrt(deg) ----
__global__ void k_scanfin(const int* __restrict__ deg, const int* __restrict__ bsum,
                          int* __restrict__ off, float* __restrict__ dinv,
                          float* __restrict__ dsq, int N) {
    __shared__ int sm[SBLK];
    int i = blockIdx.x * SBLK + threadIdx.x;
    int v = (i < N) ? deg[i] : 0;
    sm[threadIdx.x] = v;
    __syncthreads();
    for (int s = 1; s < SBLK; s <<= 1) {
        int u = (threadIdx.x >= s) ? sm[threadIdx.x - s] : 0;
        __syncthreads();
        sm[threadIdx.x] += u;
        __syncthreads();
    }
    int ex = sm[threadIdx.x] - v + bsum[blockIdx.x];
    if (i < N) {
        off[i]  = ex;
        dinv[i] = v > 0 ? rsqrtf((float)v) : 0.0f;
        dsq[i]  = v > 0 ? sqrtf((float)v) : 0.0f;
    }
}

// ---- CSR fill: no atomics — slot = off[dst] + rank ----
__global__ void k_fill(const int* __restrict__ src, const int* __restrict__ dst,
                       const int* __restrict__ rank, const int* __restrict__ off,
                       int* __restrict__ col, int E) {
    int e = blockIdx.x * blockDim.x + threadIdx.x;
    if (e >= E) return;
    col[off[dst[e]] + rank[e]] = src[e];
}

// ---- out1 = E0 ; y0 = fp16(dinv * E0). one thread per 8 elements ----
__global__ void k_init(const float* __restrict__ e0, const float* __restrict__ dinv,
                       float* __restrict__ out1, __half* __restrict__ y0, int n8) {
    int i = blockIdx.x * blockDim.x + threadIdx.x;
    if (i >= n8) return;
    size_t o = (size_t)i * 8;
    float4 a = *reinterpret_cast<const float4*>(e0 + o);
    float4 b = *reinterpret_cast<const float4*>(e0 + o + 4);
    *reinterpret_cast<float4*>(out1 + o)     = a;
    *reinterpret_cast<float4*>(out1 + o + 4) = b;
    float dv = dinv[i >> 3];
    H8 u;
    u.h2[0] = __floats2half2_rn(dv * a.x, dv * a.y);
    u.h2[1] = __floats2half2_rn(dv * a.z, dv * a.w);
    u.h2[2] = __floats2half2_rn(dv * b.x, dv * b.y);
    u.h2[3] = __floats2half2_rn(dv * b.z, dv * b.w);
    *reinterpret_cast<uint4*>(y0 + o) = u.u;
}

// ---- pull-propagate (fp16 rows): y_out[d] = dinv[d]^2 * sum_{s->d} y_in[s] ----
// 1 wave per node, 8 edge slots x 8 lanes x 8 halves
__global__ __launch_bounds__(256) void k_prop(const __half* __restrict__ y,
        const int* __restrict__ off, const int* __restrict__ col,
        const float* __restrict__ dinv, __half* __restrict__ yout, int N) {
    int wid = (blockIdx.x * 256 + threadIdx.x) >> 6;
    if (wid >= N) return;
    int lane = threadIdx.x & 63;
    int es   = lane >> 3;      // edge slot 0..7
    int ch   = lane & 7;       // 8-half chunk 0..7
    int s = off[wid], e = off[wid + 1];

    float acc[8];
#pragma unroll
    for (int k = 0; k < 8; ++k) acc[k] = 0.f;

    for (int j = s + es; j < e; j += 8) {
        H8 u;
        u.u = *reinterpret_cast<const uint4*>(y + (size_t)col[j] * DIM + ch * 8);
        float2 f0 = __half22float2(u.h2[0]);
        float2 f1 = __half22float2(u.h2[1]);
        float2 f2 = __half22float2(u.h2[2]);
        float2 f3 = __half22float2(u.h2[3]);
        acc[0] += f0.x; acc[1] += f0.y; acc[2] += f1.x; acc[3] += f1.y;
        acc[4] += f2.x; acc[5] += f2.y; acc[6] += f3.x; acc[7] += f3.y;
    }
#pragma unroll
    for (int k = 0; k < 8; ++k) {
        acc[k] += __shfl_xor(acc[k], 8);
        acc[k] += __shfl_xor(acc[k], 16);
        acc[k] += __shfl_xor(acc[k], 32);
    }
    if (es == 0) {
        float dv = dinv[wid];
        float s2 = dv * dv;
        H8 u;
        u.h2[0] = __floats2half2_rn(s2 * acc[0], s2 * acc[1]);
        u.h2[1] = __floats2half2_rn(s2 * acc[2], s2 * acc[3]);
        u.h2[2] = __floats2half2_rn(s2 * acc[4], s2 * acc[5]);
        u.h2[3] = __floats2half2_rn(s2 * acc[6], s2 * acc[7]);
        *reinterpret_cast<uint4*>(yout + (size_t)wid * DIM + ch * 8) = u.u;
    }
}

// ---- final: out2 = 0.25*(E0 + sqrt(deg)*(y1+y2) + dinv*sum(y2[s])) ----
__global__ __launch_bounds__(256) void k_prop_final(const __half* __restrict__ y2,
        const int* __restrict__ off, const int* __restrict__ col,
        const float* __restrict__ dinv, const float* __restrict__ dsq,
        const float* __restrict__ e0, const __half* __restrict__ y1b,
        const __half* __restrict__ y2b, float* __restrict__ out2, int N) {
    int wid = (blockIdx.x * 256 + threadIdx.x) >> 6;
    if (wid >= N) return;
    int lane = threadIdx.x & 63;
    int es   = lane >> 3;
    int ch   = lane & 7;
    int s = off[wid], e = off[wid + 1];

    float acc[8];
#pragma unroll
    for (int k = 0; k < 8; ++k) acc[k] = 0.f;

    for (int j = s + es; j < e; j += 8) {
        H8 u;
        u.u = *reinterpret_cast<const uint4*>(y2 + (size_t)col[j] * DIM + ch * 8);
        float2 f0 = __half22float2(u.h2[0]);
        float2 f1 = __half22float2(u.h2[1]);
        float2 f2 = __half22float2(u.h2[2]);
        float2 f3 = __half22float2(u.h2[3]);
        acc[0] += f0.x; acc[1] += f0.y; acc[2] += f1.x; acc[3] += f1.y;
        acc[4] += f2.x; acc[5] += f2.y; acc[6] += f3.x; acc[7] += f3.y;
    }
#pragma unroll
    for (int k = 0; k < 8; ++k) {
        acc[k] += __shfl_xor(acc[k], 8);
        acc[k] += __shfl_xor(acc[k], 16);
        acc[k] += __shfl_xor(acc[k], 32);
    }
    if (es == 0) {
        float dv = dinv[wid];
        float dq = dsq[wid];
        size_t o = (size_t)wid * DIM + ch * 8;
        float4 ea = *reinterpret_cast<const float4*>(e0 + o);
        float4 eb = *reinterpret_cast<const float4*>(e0 + o + 4);
        H8 u1; u1.u = *reinterpret_cast<const uint4*>(y1b + o);
        H8 u2; u2.u = *reinterpret_cast<const uint4*>(y2b + o);
        float2 p0 = __half22float2(u1.h2[0]), q0 = __half22float2(u2.h2[0]);
        float2 p1 = __half22float2(u1.h2[1]), q1 = __half22float2(u2.h2[1]);
        float2 p2 = __half22float2(u1.h2[2]), q2 = __half22float2(u2.h2[2]);
        float2 p3 = __half22float2(u1.h2[3]), q3 = __half22float2(u2.h2[3]);
        float4 ra, rb;
        ra.x = 0.25f * (ea.x + dq * (p0.x + q0.x) + dv * acc[0]);
        ra.y = 0.25f * (ea.y + dq * (p0.y + q0.y) + dv * acc[1]);
        ra.z = 0.25f * (ea.z + dq * (p1.x + q1.x) + dv * acc[2]);
        ra.w = 0.25f * (ea.w + dq * (p1.y + q1.y) + dv * acc[3]);
        rb.x = 0.25f * (eb.x + dq * (p2.x + q2.x) + dv * acc[4]);
        rb.y = 0.25f * (eb.y + dq * (p2.y + q2.y) + dv * acc[5]);
        rb.z = 0.25f * (eb.z + dq * (p3.x + q3.x) + dv * acc[6]);
        rb.w = 0.25f * (eb.w + dq * (p3.y + q3.y) + dv * acc[7]);
        *reinterpret_cast<float4*>(out2 + o)     = ra;
        *reinterpret_cast<float4*>(out2 + o + 4) = rb;
    }
}

extern "C" void kernel_launch(void* const* d_in, const int* in_sizes, int n_in,
                              void* d_out, int out_size, void* d_ws, size_t ws_size,
                              hipStream_t stream) {
    const float* E0  = (const float*)d_in[0];
    const int*   idx = (const int*)d_in[1];

    const int N = in_sizes[0] / DIM;   // 100000
    const int E = in_sizes[1] / 2;     // 1000000

    const int* src = idx;
    const int* dst = idx + E;

    float* out1 = (float*)d_out;                     // E0 copy
    float* out2 = (float*)d_out + (size_t)N * DIM;   // final embeddings

    const int NB = (N + SBLK - 1) / SBLK;            // scan blocks (391)

    // workspace layout — every carve rounded to 16 B
    char* ws = (char*)d_ws;
    auto carve = [&](size_t bytes) -> char* {
        char* p = ws;
        ws += (bytes + 15) & ~(size_t)15;
        return p;
    };
    int*    deg  = (int*)   carve((size_t)N * 4);
    int*    off  = (int*)   carve((size_t)(N + 1) * 4);
    int*    bsum = (int*)   carve((size_t)NB * 4);
    float*  dinv = (float*) carve((size_t)N * 4);
    float*  dsq  = (float*) carve((size_t)N * 4);
    int*    rank = (int*)   carve((size_t)E * 4);
    int*    col  = (int*)   carve((size_t)E * 4);
    __half* y0   = (__half*)carve((size_t)N * DIM * 2);
    __half* y1   = (__half*)carve((size_t)N * DIM * 2);
    __half* y2   = (__half*)carve((size_t)N * DIM * 2);

    const int n8 = N * DIM / 8;

    hipMemsetAsync(deg, 0, (size_t)N * sizeof(int), stream);

    k_hist   <<<(E + 255) / 256, 256, 0, stream>>>(dst, deg, rank, E);
    k_bsum   <<<NB, SBLK, 0, stream>>>(deg, bsum, N);
    k_scanb  <<<1, 1024, 0, stream>>>(bsum, NB, &off[N], E);
    k_scanfin<<<NB, SBLK, 0, stream>>>(deg, bsum, off, dinv, dsq, N);
    k_fill   <<<(E + 255) / 256, 256, 0, stream>>>(src, dst, rank, off, col, E);

    k_init   <<<(n8 + 255) / 256, 256, 0, stream>>>(E0, dinv, out1, y0, n8);

    const int PB = (N + 3) / 4;   // one 64-lane wave per node
    // layer 1: y0 -> y1
    k_prop<<<PB, 256, 0, stream>>>(y0, off, col, dinv, y1, N);
    // layer 2: y1 -> y2
    k_prop<<<PB, 256, 0, stream>>>(y1, off, col, dinv, y2, N);
    // layer 3 + final combine, fused
    k_prop_final<<<PB, 256, 0, stream>>>(y2, off, col, dinv, dsq,
                                         E0, y1, y2, out2, N);
}